// Round 3
// baseline (146.476 us; speedup 1.0000x reference)
//
#include <hip/hip_runtime.h>

// Fully fused: conv(2x2 dot)+sigmoid -> concat -> Linear(3,4)+tanh ->
// Linear(4,2)+softmax. Memory-bound: 32 B/sample x 4.19M = 134 MB, floor
// ~22 us at ~6.3 TB/s. 4 samples/thread: 6x 16B loads + 2x 16B stores per
// thread, all loads issued before compute (max memory-level parallelism).
// Nontemporal (streamed, never re-read). Raw v_rcp -- threshold 1.9e-2.

using f32x4 = __attribute__((ext_vector_type(4))) float;

__device__ __forceinline__ float raw_rcp(float x) {
    return __builtin_amdgcn_rcpf(x);
}
__device__ __forceinline__ float fast_sigmoid(float x) {
    return raw_rcp(1.0f + __expf(-x));
}
__device__ __forceinline__ float fast_tanh(float x) {
    // 1 - 2/(e^{2x}+1); saturates to +/-1 when exp over/underflows (rcp(inf)=0)
    return 1.0f - 2.0f * raw_rcp(__expf(2.0f * x) + 1.0f);
}

__global__ __launch_bounds__(256) void HybridSamplerConv_kernel(
    const float* __restrict__ inputs,   // [B,2]
    const float* __restrict__ data,     // [B,2,2]
    const float* __restrict__ conv_w,   // [2,2]
    const float* __restrict__ conv_b,   // scalar
    const float* __restrict__ w1,       // [3,4]
    const float* __restrict__ b1,       // [4]
    const float* __restrict__ w2,       // [4,2]
    const float* __restrict__ b2,       // [2]
    float* __restrict__ out,            // [B,2]
    int B)
{
    // Wave-uniform parameter loads -> scalar loads into SGPRs.
    const float cw0 = conv_w[0], cw1 = conv_w[1], cw2 = conv_w[2], cw3 = conv_w[3];
    const float cb  = conv_b[0];
    float W1[12];
#pragma unroll
    for (int i = 0; i < 12; ++i) W1[i] = w1[i];
    float B1[4];
#pragma unroll
    for (int i = 0; i < 4; ++i) B1[i] = b1[i];
    float W2[8];
#pragma unroll
    for (int i = 0; i < 8; ++i) W2[i] = w2[i];
    const float b20 = b2[0], b21 = b2[1];

    const int q = blockIdx.x * 256 + threadIdx.x;   // quad index: samples 4q..4q+3
    if (4 * q + 3 >= B) return;                     // B divisible by 4; quads never split

    // Issue ALL global loads before any dependent compute (6 outstanding).
    const f32x4 xinA = __builtin_nontemporal_load((const f32x4*)inputs + 2 * q);     // s0,s1
    const f32x4 xinB = __builtin_nontemporal_load((const f32x4*)inputs + 2 * q + 1); // s2,s3
    f32x4 d[4];
#pragma unroll
    for (int k = 0; k < 4; ++k)
        d[k] = __builtin_nontemporal_load((const f32x4*)data + 4 * q + k);

    f32x4 oA, oB;

#pragma unroll
    for (int k = 0; k < 4; ++k) {
        const float ix = (k == 0) ? xinA.x : (k == 1) ? xinA.z : (k == 2) ? xinB.x : xinB.z;
        const float iy = (k == 0) ? xinA.y : (k == 1) ? xinA.w : (k == 2) ? xinB.y : xinB.w;

        // conv 2x2 -> single logit; mean over 1x1 map is identity
        const float logit = d[k].x * cw0 + d[k].y * cw1 + d[k].z * cw2 + d[k].w * cw3 + cb;
        const float conv  = fast_sigmoid(logit);

        // h = tanh([ix,iy,conv] @ W1 + b1)
        float h[4];
#pragma unroll
        for (int j = 0; j < 4; ++j) {
            const float pre = ix * W1[j] + iy * W1[4 + j] + conv * W1[8 + j] + B1[j];
            h[j] = fast_tanh(pre);
        }

        // z = h @ W2 + b2 ; 2-way softmax
        const float z0 = h[0] * W2[0] + h[1] * W2[2] + h[2] * W2[4] + h[3] * W2[6] + b20;
        const float z1 = h[0] * W2[1] + h[1] * W2[3] + h[2] * W2[5] + h[3] * W2[7] + b21;
        const float o0 = raw_rcp(1.0f + __expf(z1 - z0));
        const float o1 = 1.0f - o0;

        if      (k == 0) { oA.x = o0; oA.y = o1; }
        else if (k == 1) { oA.z = o0; oA.w = o1; }
        else if (k == 2) { oB.x = o0; oB.y = o1; }
        else             { oB.z = o0; oB.w = o1; }
    }

    __builtin_nontemporal_store(oA, (f32x4*)out + 2 * q);
    __builtin_nontemporal_store(oB, (f32x4*)out + 2 * q + 1);
}

extern "C" void kernel_launch(void* const* d_in, const int* in_sizes, int n_in,
                              void* d_out, int out_size, void* d_ws, size_t ws_size,
                              hipStream_t stream) {
    const float* inputs = (const float*)d_in[0];
    const float* data   = (const float*)d_in[1];
    const float* conv_w = (const float*)d_in[2];
    const float* conv_b = (const float*)d_in[3];
    const float* w1     = (const float*)d_in[4];
    const float* b1     = (const float*)d_in[5];
    const float* w2     = (const float*)d_in[6];
    const float* b2     = (const float*)d_in[7];
    float* out          = (float*)d_out;

    const int B = in_sizes[0] / 2;            // 4194304
    const int quads = (B + 3) / 4;            // 1048576
    const int blocks = (quads + 255) / 256;   // 4096
    HybridSamplerConv_kernel<<<blocks, 256, 0, stream>>>(
        inputs, data, conv_w, conv_b, w1, b1, w2, b2, out, B);
}